// Round 7
// baseline (932.985 us; speedup 1.0000x reference)
//
#include <hip/hip_runtime.h>

#define N_COL 100000
#define N_CON 20000
#define HDIM 128
#define SCAN_B 1024  // elements scanned per block (256 thr x 4)

// ---------- tiny transpose: dst[c*R+r] = src[r*C+c] ----------
__global__ void transpose_k(const float* __restrict__ src, float* __restrict__ dst, int R, int C) {
    int idx = blockIdx.x * blockDim.x + threadIdx.x;
    if (idx < R * C) {
        int r = idx / C, c = idx - r * C;
        dst[c * R + r] = src[idx];
    }
}

// ---------- encoder: out[n,h] = relu(sum_k x[n,k]*WT[k,h] + b[h]) ----------
template <int D>
__global__ __launch_bounds__(256) void encoder_k(const float* __restrict__ x,
                                                 const float* __restrict__ WT,
                                                 const float* __restrict__ b,
                                                 float* __restrict__ out, int N) {
    int idx = blockIdx.x * blockDim.x + threadIdx.x;
    if (idx >= N * HDIM) return;
    int n = idx >> 7, h = idx & 127;
    const float* xr = x + (size_t)n * D;
    float acc = b[h];
#pragma unroll
    for (int k = 0; k < D; k++) acc = fmaf(xr[k], WT[k * HDIM + h], acc);
    out[idx] = fmaxf(acc, 0.f);
}

// ---------- CSR build: counts ----------
__global__ void count_k(const int* __restrict__ ecol, const int* __restrict__ econ,
                        int* cnt_col, int* cnt_con, int E) {
    int e = blockIdx.x * blockDim.x + threadIdx.x;
    if (e < E) {
        atomicAdd(&cnt_col[ecol[e]], 1);
        atomicAdd(&cnt_con[econ[e]], 1);
    }
}

// ---------- 3-phase exclusive scan ----------
__global__ __launch_bounds__(256) void scan1_k(const int* __restrict__ cnt, int n,
                                               int* __restrict__ offs, int* __restrict__ partials) {
    __shared__ int lds[256];
    int t = threadIdx.x;
    int base = blockIdx.x * SCAN_B + t * 4;
    int v[4], s = 0;
#pragma unroll
    for (int i = 0; i < 4; i++) { int idx = base + i; v[i] = (idx < n) ? cnt[idx] : 0; s += v[i]; }
    lds[t] = s; __syncthreads();
    for (int off = 1; off < 256; off <<= 1) {
        int x = (t >= off) ? lds[t - off] : 0; __syncthreads();
        lds[t] += x; __syncthreads();
    }
    int excl = lds[t] - s;
    if (t == 255) partials[blockIdx.x] = lds[255];
    int run = excl;
#pragma unroll
    for (int i = 0; i < 4; i++) { int idx = base + i; if (idx < n) offs[idx] = run; run += v[i]; }
}

__global__ __launch_bounds__(256) void scan2_k(int* partials, int nb) {  // nb <= 256, single block
    __shared__ int lds[256];
    int t = threadIdx.x;
    int v = (t < nb) ? partials[t] : 0;
    lds[t] = v; __syncthreads();
    for (int off = 1; off < 256; off <<= 1) {
        int x = (t >= off) ? lds[t - off] : 0; __syncthreads();
        lds[t] += x; __syncthreads();
    }
    if (t < nb) partials[t] = lds[t] - v;  // exclusive
}

__global__ void scan3_k(int* offs, int n, const int* __restrict__ partials) {
    int i = blockIdx.x * blockDim.x + threadIdx.x;
    if (i < n) offs[i] += partials[i / SCAN_B];
}

// ---------- CSR fill: srclist bucketed by destination ----------
__global__ void fill_k(const int* __restrict__ sidx, const int* __restrict__ didx,
                       const int* __restrict__ offs, int* cursor, int* __restrict__ srclist, int E) {
    int e = blockIdx.x * blockDim.x + threadIdx.x;
    if (e < E) {
        int d = didx[e];
        int p = offs[d] + atomicAdd(&cursor[d], 1);
        srclist[p] = sidx[e];
    }
}

// ======== fused conv: gather-mean -> LDS, then dual GEMM from LDS ========
// Block = 64 dst nodes. LDS: As[64][132] (33792 B) + Ws[32][132] (16896 B) = 50688 B.
// Gather: each wave runs 4 nodes concurrently (16 lanes/node, lane owns 8 cols).
// GEMM: BM=64, BN=128, BK=32; thread = 4 rows x 8 cols (cols tx*4 and 64+tx*4).

#define FUSED_GATHER(TAB)                                                                   \
    {                                                                                       \
        int lane = t & 63, wid = t >> 6;                                                    \
        int sub = lane >> 4, lx = lane & 15, q8 = lx * 8;                                   \
        for (int u = 0; u < 4; ++u) {                                                       \
            int nl = wid * 16 + u * 4 + sub;                                                \
            int n = n0 + nl;                                                                \
            int c = 0, st = 0;                                                              \
            if (n < N) { c = cnt[n]; st = offs[n]; }                                        \
            const int* sl = srclist + st;                                                   \
            float a0 = 0.f, a1 = 0.f, a2 = 0.f, a3 = 0.f;                                   \
            float a4_ = 0.f, a5 = 0.f, a6 = 0.f, a7 = 0.f;                                  \
            for (int j = 0; j < c; ++j) {                                                   \
                const float* rp = TAB + (size_t)sl[j] * HDIM + q8;                          \
                float4 v0 = *reinterpret_cast<const float4*>(rp);                           \
                float4 v1 = *reinterpret_cast<const float4*>(rp + 4);                       \
                a0 += v0.x; a1 += v0.y; a2 += v0.z; a3 += v0.w;                             \
                a4_ += v1.x; a5 += v1.y; a6 += v1.z; a7 += v1.w;                            \
            }                                                                               \
            float inv = 1.f / fmaxf((float)c, 1.f);                                         \
            float4 r0, r1;                                                                  \
            r0.x = a0 * inv; r0.y = a1 * inv; r0.z = a2 * inv; r0.w = a3 * inv;             \
            r1.x = a4_ * inv; r1.y = a5 * inv; r1.z = a6 * inv; r1.w = a7 * inv;            \
            *reinterpret_cast<float4*>(&As[nl][q8]) = r0;                                   \
            *reinterpret_cast<float4*>(&As[nl][q8 + 4]) = r1;                               \
        }                                                                                   \
    }

#define FUSED_XSTAGE(XDST)                                                                  \
    {                                                                                       \
        int xr = t >> 2, xc0 = (t & 3) * 32;                                                \
        int row = n0 + xr;                                                                  \
        if (row < N) {                                                                      \
            const float* xp = XDST + (size_t)row * HDIM + xc0;                              \
            _Pragma("unroll")                                                               \
            for (int jj = 0; jj < 8; jj++)                                                  \
                *reinterpret_cast<float4*>(&As[xr][xc0 + 4 * jj]) =                         \
                    *reinterpret_cast<const float4*>(xp + 4 * jj);                          \
        } else {                                                                            \
            float4 z = make_float4(0.f, 0.f, 0.f, 0.f);                                     \
            _Pragma("unroll")                                                               \
            for (int jj = 0; jj < 8; jj++)                                                  \
                *reinterpret_cast<float4*>(&As[xr][xc0 + 4 * jj]) = z;                      \
        }                                                                                   \
    }

#define GEMM_HALF(WPTR)                                                                     \
    for (int kb = 0; kb < 4; ++kb) {                                                        \
        {                                                                                   \
            const float* wp = WPTR + (size_t)(kb * 32 + wk) * HDIM + wc;                    \
            _Pragma("unroll")                                                               \
            for (int jj = 0; jj < 4; jj++)                                                  \
                *reinterpret_cast<float4*>(&Ws[wk][wc + 4 * jj]) =                          \
                    *reinterpret_cast<const float4*>(wp + 4 * jj);                          \
        }                                                                                   \
        __syncthreads();                                                                    \
        _Pragma("unroll")                                                                   \
        for (int k4 = 0; k4 < 8; ++k4) {                                                    \
            float4 av[4];                                                                   \
            _Pragma("unroll")                                                               \
            for (int i = 0; i < 4; i++)                                                     \
                av[i] = *reinterpret_cast<const float4*>(&As[ty * 4 + i][kb * 32 + k4 * 4]);\
            _Pragma("unroll")                                                               \
            for (int kk = 0; kk < 4; kk++) {                                                \
                float4 w0 = *reinterpret_cast<const float4*>(&Ws[k4 * 4 + kk][tx * 4]);     \
                float4 w1 = *reinterpret_cast<const float4*>(&Ws[k4 * 4 + kk][64 + tx * 4]);\
                float w[8] = {w0.x, w0.y, w0.z, w0.w, w1.x, w1.y, w1.z, w1.w};              \
                _Pragma("unroll")                                                           \
                for (int i = 0; i < 4; i++) {                                               \
                    float avk = (kk == 0) ? av[i].x : (kk == 1) ? av[i].y                   \
                                : (kk == 2) ? av[i].z : av[i].w;                            \
                    _Pragma("unroll")                                                       \
                    for (int j = 0; j < 8; j++) acc[i][j] = fmaf(avk, w[j], acc[i][j]);     \
                }                                                                           \
            }                                                                               \
        }                                                                                   \
        __syncthreads();                                                                    \
    }

// ---------- fused SAGE conv (gather + dual GEMM) ----------
__global__ __launch_bounds__(256) void sage_fused_k(const float* __restrict__ tab,
                                                    const int* __restrict__ srclist,
                                                    const int* __restrict__ offs,
                                                    const int* __restrict__ cnt,
                                                    const float* __restrict__ xdst,
                                                    const float* __restrict__ WlT,
                                                    const float* __restrict__ bl,
                                                    const float* __restrict__ WrT,
                                                    float* __restrict__ out, int N) {
    __shared__ __align__(16) char smem[50688];
    float (*As)[132] = reinterpret_cast<float(*)[132]>(smem);
    float (*Ws)[132] = reinterpret_cast<float(*)[132]>(smem + 33792);
    int t = threadIdx.x;
    int tx = t & 15, ty = t >> 4;
    int wk = t >> 3, wc = (t & 7) * 16;
    int n0 = blockIdx.x * 64;
    float acc[4][8];
#pragma unroll
    for (int i = 0; i < 4; i++)
#pragma unroll
        for (int j = 0; j < 8; j++) acc[i][j] = 0.f;

    FUSED_GATHER(tab)          // As = segment-mean rows (sync inside GEMM_HALF covers it)
    GEMM_HALF(WlT)
    FUSED_XSTAGE(xdst)         // overwrite As with dst rows (prev half ended with sync)
    GEMM_HALF(WrT)

    float4 b0 = *reinterpret_cast<const float4*>(bl + tx * 4);
    float4 b1 = *reinterpret_cast<const float4*>(bl + 64 + tx * 4);
    float bb[8] = {b0.x, b0.y, b0.z, b0.w, b1.x, b1.y, b1.z, b1.w};
#pragma unroll
    for (int i = 0; i < 4; i++) {
        int row = n0 + ty * 4 + i;
        if (row < N) {
            float4 r0, r1;
            r0.x = fmaxf(acc[i][0] + bb[0], 0.f);
            r0.y = fmaxf(acc[i][1] + bb[1], 0.f);
            r0.z = fmaxf(acc[i][2] + bb[2], 0.f);
            r0.w = fmaxf(acc[i][3] + bb[3], 0.f);
            r1.x = fmaxf(acc[i][4] + bb[4], 0.f);
            r1.y = fmaxf(acc[i][5] + bb[5], 0.f);
            r1.z = fmaxf(acc[i][6] + bb[6], 0.f);
            r1.w = fmaxf(acc[i][7] + bb[7], 0.f);
            float* op = out + (size_t)row * HDIM;
            *reinterpret_cast<float4*>(op + tx * 4) = r0;
            *reinterpret_cast<float4*>(op + 64 + tx * 4) = r1;
        }
    }
}

// ---------- fused SAGE conv + Q-head (H2 tile overlays As) ----------
__global__ __launch_bounds__(256) void sage_fused_q_k(const float* __restrict__ tab,
                                                      const int* __restrict__ srclist,
                                                      const int* __restrict__ offs,
                                                      const int* __restrict__ cnt,
                                                      const float* __restrict__ xdst,
                                                      const float* __restrict__ WlT,
                                                      const float* __restrict__ bl,
                                                      const float* __restrict__ WrT,
                                                      const float* __restrict__ W1T,
                                                      const float* __restrict__ b1v,
                                                      const float* __restrict__ W2,
                                                      const float* __restrict__ b2,
                                                      float* __restrict__ out, int N) {
    __shared__ __align__(16) char smem[50688];
    float (*As)[132] = reinterpret_cast<float(*)[132]>(smem);
    float (*Ws)[132] = reinterpret_cast<float(*)[132]>(smem + 33792);
    float (*H2)[132] = reinterpret_cast<float(*)[132]>(smem);  // overlay on As
    int t = threadIdx.x;
    int tx = t & 15, ty = t >> 4;
    int wk = t >> 3, wc = (t & 7) * 16;
    int n0 = blockIdx.x * 64;
    float acc[4][8];
#pragma unroll
    for (int i = 0; i < 4; i++)
#pragma unroll
        for (int j = 0; j < 8; j++) acc[i][j] = 0.f;

    FUSED_GATHER(tab)
    GEMM_HALF(WlT)
    FUSED_XSTAGE(xdst)
    GEMM_HALF(WrT)
    // last sync of GEMM_HALF protects As -> H2 overwrite

    // phase-1 epilogue: bias + relu -> LDS tile (H2 = As region)
    {
        float4 b0 = *reinterpret_cast<const float4*>(bl + tx * 4);
        float4 b1 = *reinterpret_cast<const float4*>(bl + 64 + tx * 4);
        float bb[8] = {b0.x, b0.y, b0.z, b0.w, b1.x, b1.y, b1.z, b1.w};
#pragma unroll
        for (int i = 0; i < 4; i++) {
            float4 r0, r1;
            r0.x = fmaxf(acc[i][0] + bb[0], 0.f);
            r0.y = fmaxf(acc[i][1] + bb[1], 0.f);
            r0.z = fmaxf(acc[i][2] + bb[2], 0.f);
            r0.w = fmaxf(acc[i][3] + bb[3], 0.f);
            r1.x = fmaxf(acc[i][4] + bb[4], 0.f);
            r1.y = fmaxf(acc[i][5] + bb[5], 0.f);
            r1.z = fmaxf(acc[i][6] + bb[6], 0.f);
            r1.w = fmaxf(acc[i][7] + bb[7], 0.f);
            float* hp = &H2[ty * 4 + i][0];
            *reinterpret_cast<float4*>(hp + tx * 4) = r0;
            *reinterpret_cast<float4*>(hp + 64 + tx * 4) = r1;
        }
    }
    __syncthreads();
    // phase 2: y = relu(H2 @ W1T + b1) [64x64]; q = y@W2 + b2
    int tx2 = t & 7, ty2 = t >> 3;
    float acc2[2][8];
#pragma unroll
    for (int i = 0; i < 2; i++)
#pragma unroll
        for (int j = 0; j < 8; j++) acc2[i][j] = 0.f;
    for (int k4 = 0; k4 < HDIM / 4; ++k4) {
        float4 a0 = *reinterpret_cast<const float4*>(&H2[ty2 * 2 + 0][k4 * 4]);
        float4 a1 = *reinterpret_cast<const float4*>(&H2[ty2 * 2 + 1][k4 * 4]);
        float a[2][4] = {{a0.x, a0.y, a0.z, a0.w}, {a1.x, a1.y, a1.z, a1.w}};
#pragma unroll
        for (int kk = 0; kk < 4; kk++) {
            const float* wp = W1T + (size_t)(k4 * 4 + kk) * 64 + tx2 * 8;
            float4 w0 = *reinterpret_cast<const float4*>(wp);
            float4 w1 = *reinterpret_cast<const float4*>(wp + 4);
            float w[8] = {w0.x, w0.y, w0.z, w0.w, w1.x, w1.y, w1.z, w1.w};
#pragma unroll
            for (int i = 0; i < 2; i++)
#pragma unroll
                for (int j = 0; j < 8; j++) acc2[i][j] = fmaf(a[i][kk], w[j], acc2[i][j]);
        }
    }
    {
        float4 c0 = *reinterpret_cast<const float4*>(b1v + tx2 * 8);
        float4 c1 = *reinterpret_cast<const float4*>(b1v + tx2 * 8 + 4);
        float bb1[8] = {c0.x, c0.y, c0.z, c0.w, c1.x, c1.y, c1.z, c1.w};
        float4 d0 = *reinterpret_cast<const float4*>(W2 + tx2 * 8);
        float4 d1 = *reinterpret_cast<const float4*>(W2 + tx2 * 8 + 4);
        float w2[8] = {d0.x, d0.y, d0.z, d0.w, d1.x, d1.y, d1.z, d1.w};
#pragma unroll
        for (int i = 0; i < 2; i++) {
            float v = 0.f;
#pragma unroll
            for (int j = 0; j < 8; j++) v = fmaf(fmaxf(acc2[i][j] + bb1[j], 0.f), w2[j], v);
            v += __shfl_xor(v, 1);
            v += __shfl_xor(v, 2);
            v += __shfl_xor(v, 4);
            int row = n0 + ty2 * 2 + i;
            if (tx2 == 0 && row < N) out[row] = v + b2[0];
        }
    }
}

extern "C" void kernel_launch(void* const* d_in, const int* in_sizes, int n_in,
                              void* d_out, int out_size, void* d_ws, size_t ws_size,
                              hipStream_t stream) {
    const float* x_col = (const float*)d_in[0];
    const float* x_con = (const float*)d_in[1];
    const int* edge_col = (const int*)d_in[2];
    const int* edge_con = (const int*)d_in[3];
    const float* W_col = (const float*)d_in[4];
    const float* b_col = (const float*)d_in[5];
    const float* W_con = (const float*)d_in[6];
    const float* b_con = (const float*)d_in[7];
    const float* c1_cn_Wl = (const float*)d_in[8];
    const float* c1_cn_bl = (const float*)d_in[9];
    const float* c1_cn_Wr = (const float*)d_in[10];
    const float* c1_nc_Wl = (const float*)d_in[11];
    const float* c1_nc_bl = (const float*)d_in[12];
    const float* c1_nc_Wr = (const float*)d_in[13];
    // d_in[14..16] = c2_cn_* : dead (h_con2 deleted in reference)
    const float* c2_nc_Wl = (const float*)d_in[17];
    const float* c2_nc_bl = (const float*)d_in[18];
    const float* c2_nc_Wr = (const float*)d_in[19];
    const float* q_W1 = (const float*)d_in[20];
    const float* q_b1 = (const float*)d_in[21];
    const float* q_W2 = (const float*)d_in[22];
    const float* q_b2 = (const float*)d_in[23];
    float* out = (float*)d_out;
    const int E = in_sizes[2];

    float* ws = (float*)d_ws;
    size_t o = 0;
    float* h_col = ws + o;   o += (size_t)N_COL * HDIM;
    float* h_con = ws + o;   o += (size_t)N_CON * HDIM;
    float* n_con = ws + o;   o += (size_t)N_CON * HDIM;
    float* n_col = ws + o;   o += (size_t)N_COL * HDIM;
    float* W_colT = ws + o;  o += 16 * HDIM;
    float* W_conT = ws + o;  o += 8 * HDIM;
    float* c1_cn_WlT = ws + o; o += HDIM * HDIM;
    float* c1_cn_WrT = ws + o; o += HDIM * HDIM;
    float* c1_nc_WlT = ws + o; o += HDIM * HDIM;
    float* c1_nc_WrT = ws + o; o += HDIM * HDIM;
    float* c2_nc_WlT = ws + o; o += HDIM * HDIM;
    float* c2_nc_WrT = ws + o; o += HDIM * HDIM;
    float* q_W1T = ws + o;     o += HDIM * 64;
    // CSR scratch (int views)
    int* iws = (int*)(ws + o);
    size_t io = 0;
    int* cnt_col = iws + io;  io += N_COL;
    int* cnt_con = iws + io;  io += N_CON;
    int* offs_col = iws + io; io += N_COL;
    int* offs_con = iws + io; io += N_CON;
    int* cursor = iws + io;   io += N_COL;  // reused for both fills
    int* partials = iws + io; io += 256;
    int* srclist_col = iws + io; io += E;   // dst=col buckets, stores con src idx
    int* srclist_con = iws + io; io += E;   // dst=con buckets, stores col src idx

    auto T = [&](const float* s, float* d, int R, int C) {
        transpose_k<<<(R * C + 255) / 256, 256, 0, stream>>>(s, d, R, C);
    };
    T(W_col, W_colT, HDIM, 16);
    T(W_con, W_conT, HDIM, 8);
    T(c1_cn_Wl, c1_cn_WlT, HDIM, HDIM);
    T(c1_cn_Wr, c1_cn_WrT, HDIM, HDIM);
    T(c1_nc_Wl, c1_nc_WlT, HDIM, HDIM);
    T(c1_nc_Wr, c1_nc_WrT, HDIM, HDIM);
    T(c2_nc_Wl, c2_nc_WlT, HDIM, HDIM);
    T(c2_nc_Wr, c2_nc_WrT, HDIM, HDIM);
    T(q_W1, q_W1T, 64, HDIM);

    encoder_k<16><<<((size_t)N_COL * HDIM + 255) / 256, 256, 0, stream>>>(x_col, W_colT, b_col, h_col, N_COL);
    encoder_k<8><<<((size_t)N_CON * HDIM + 255) / 256, 256, 0, stream>>>(x_con, W_conT, b_con, h_con, N_CON);

    // ---- CSR build (both directions) ----
    hipMemsetAsync(cnt_col, 0, (N_COL + N_CON) * sizeof(int), stream);  // cnt_col+cnt_con contiguous
    count_k<<<(E + 255) / 256, 256, 0, stream>>>(edge_col, edge_con, cnt_col, cnt_con, E);

    int nb_col = (N_COL + SCAN_B - 1) / SCAN_B;  // 98
    int nb_con = (N_CON + SCAN_B - 1) / SCAN_B;  // 20
    scan1_k<<<nb_col, 256, 0, stream>>>(cnt_col, N_COL, offs_col, partials);
    scan2_k<<<1, 256, 0, stream>>>(partials, nb_col);
    scan3_k<<<(N_COL + 255) / 256, 256, 0, stream>>>(offs_col, N_COL, partials);
    scan1_k<<<nb_con, 256, 0, stream>>>(cnt_con, N_CON, offs_con, partials);
    scan2_k<<<1, 256, 0, stream>>>(partials, nb_con);
    scan3_k<<<(N_CON + 255) / 256, 256, 0, stream>>>(offs_con, N_CON, partials);

    hipMemsetAsync(cursor, 0, N_COL * sizeof(int), stream);
    fill_k<<<(E + 255) / 256, 256, 0, stream>>>(edge_con, edge_col, offs_col, cursor, srclist_col, E);
    hipMemsetAsync(cursor, 0, N_CON * sizeof(int), stream);
    fill_k<<<(E + 255) / 256, 256, 0, stream>>>(edge_col, edge_con, offs_con, cursor, srclist_con, E);

    // ---- conv1 col->con (fused gather+GEMM) ----
    sage_fused_k<<<(N_CON + 63) / 64, 256, 0, stream>>>(h_col, srclist_con, offs_con, cnt_con,
                                                        h_con, c1_cn_WlT, c1_cn_bl, c1_cn_WrT, n_con, N_CON);
    // ---- conv1 con->col ----
    sage_fused_k<<<(N_COL + 63) / 64, 256, 0, stream>>>(h_con, srclist_col, offs_col, cnt_col,
                                                        h_col, c1_nc_WlT, c1_nc_bl, c1_nc_WrT, n_col, N_COL);
    // ---- conv2 con->col + fused Q-head ----
    sage_fused_q_k<<<(N_COL + 63) / 64, 256, 0, stream>>>(n_con, srclist_col, offs_col, cnt_col,
                                                          n_col, c2_nc_WlT, c2_nc_bl, c2_nc_WrT,
                                                          q_W1T, q_b1, q_W2, q_b2, out, N_COL);
}

// Round 8
// 743.305 us; speedup vs baseline: 1.2552x; 1.2552x over previous
//
#include <hip/hip_runtime.h>

#define N_COL 100000
#define N_CON 20000
#define HDIM 128
#define SCAN_B 1024  // elements scanned per block (256 thr x 4)

// ---------- tiny transpose: dst[c*R+r] = src[r*C+c] ----------
__global__ void transpose_k(const float* __restrict__ src, float* __restrict__ dst, int R, int C) {
    int idx = blockIdx.x * blockDim.x + threadIdx.x;
    if (idx < R * C) {
        int r = idx / C, c = idx - r * C;
        dst[c * R + r] = src[idx];
    }
}

// ---------- encoder: out[n,h] = relu(sum_k x[n,k]*WT[k,h] + b[h]) ----------
template <int D>
__global__ __launch_bounds__(256) void encoder_k(const float* __restrict__ x,
                                                 const float* __restrict__ WT,
                                                 const float* __restrict__ b,
                                                 float* __restrict__ out, int N) {
    int idx = blockIdx.x * blockDim.x + threadIdx.x;
    if (idx >= N * HDIM) return;
    int n = idx >> 7, h = idx & 127;
    const float* xr = x + (size_t)n * D;
    float acc = b[h];
#pragma unroll
    for (int k = 0; k < D; k++) acc = fmaf(xr[k], WT[k * HDIM + h], acc);
    out[idx] = fmaxf(acc, 0.f);
}

// ---------- CSR build ----------
__global__ void count_k(const int* __restrict__ ecol, const int* __restrict__ econ,
                        int* cnt_col, int* cnt_con, int E) {
    int e = blockIdx.x * blockDim.x + threadIdx.x;
    if (e < E) {
        atomicAdd(&cnt_col[ecol[e]], 1);
        atomicAdd(&cnt_con[econ[e]], 1);
    }
}

__global__ __launch_bounds__(256) void scan1_k(const int* __restrict__ cnt, int n,
                                               int* __restrict__ offs, int* __restrict__ partials) {
    __shared__ int lds[256];
    int t = threadIdx.x;
    int base = blockIdx.x * SCAN_B + t * 4;
    int v[4], s = 0;
#pragma unroll
    for (int i = 0; i < 4; i++) { int idx = base + i; v[i] = (idx < n) ? cnt[idx] : 0; s += v[i]; }
    lds[t] = s; __syncthreads();
    for (int off = 1; off < 256; off <<= 1) {
        int x = (t >= off) ? lds[t - off] : 0; __syncthreads();
        lds[t] += x; __syncthreads();
    }
    int excl = lds[t] - s;
    if (t == 255) partials[blockIdx.x] = lds[255];
    int run = excl;
#pragma unroll
    for (int i = 0; i < 4; i++) { int idx = base + i; if (idx < n) offs[idx] = run; run += v[i]; }
}

__global__ __launch_bounds__(256) void scan2_k(int* partials, int nb) {
    __shared__ int lds[256];
    int t = threadIdx.x;
    int v = (t < nb) ? partials[t] : 0;
    lds[t] = v; __syncthreads();
    for (int off = 1; off < 256; off <<= 1) {
        int x = (t >= off) ? lds[t - off] : 0; __syncthreads();
        lds[t] += x; __syncthreads();
    }
    if (t < nb) partials[t] = lds[t] - v;
}

__global__ void scan3_k(int* offs, int n, const int* __restrict__ partials) {
    int i = blockIdx.x * blockDim.x + threadIdx.x;
    if (i < n) offs[i] += partials[i / SCAN_B];
}

__global__ void fill_k(const int* __restrict__ sidx, const int* __restrict__ didx,
                       const int* __restrict__ offs, int* cursor, int* __restrict__ srclist, int E) {
    int e = blockIdx.x * blockDim.x + threadIdx.x;
    if (e < E) {
        int d = didx[e];
        int p = offs[d] + atomicAdd(&cursor[d], 1);
        srclist[p] = sidx[e];
    }
}

// ---------- gather segment-mean: one wave per dst node (R6 version) ----------
__global__ __launch_bounds__(256) void gather_mean_k(const float* __restrict__ tab,
                                                     const int* __restrict__ srclist,
                                                     const int* __restrict__ offs,
                                                     const int* __restrict__ cnt,
                                                     float* __restrict__ out, int N) {
    int wid = threadIdx.x >> 6, lane = threadIdx.x & 63;
    int n = blockIdx.x * 4 + wid;
    if (n >= N) return;
    int c = cnt[n], st = offs[n];
    const int* sl = srclist + st;
    int half = lane >> 5, q = (lane & 31) * 4;
    float ax = 0.f, ay = 0.f, az = 0.f, aw = 0.f;
    int j = 0;
    for (; j + 1 < c; j += 2) {
        int s = sl[j + half];
        float4 a = *reinterpret_cast<const float4*>(tab + (size_t)s * HDIM + q);
        ax += a.x; ay += a.y; az += a.z; aw += a.w;
    }
    if (j < c && half == 0) {
        int s = sl[j];
        float4 a = *reinterpret_cast<const float4*>(tab + (size_t)s * HDIM + q);
        ax += a.x; ay += a.y; az += a.z; aw += a.w;
    }
    ax += __shfl_xor(ax, 32); ay += __shfl_xor(ay, 32);
    az += __shfl_xor(az, 32); aw += __shfl_xor(aw, 32);
    if (half == 0) {
        float inv = 1.f / fmaxf((float)c, 1.f);
        float4 r; r.x = ax * inv; r.y = ay * inv; r.z = az * inv; r.w = aw * inv;
        *reinterpret_cast<float4*>(out + (size_t)n * HDIM + q) = r;
    }
}

// ======== GEMM core: one K=128 pass, As[64][36] per-32k staging, float4 A reads ========
// thread = 4 rows (ty*4..+3) x 8 cols (tx*4..+3, 64+tx*4..+3)
__device__ __forceinline__ void gemm_core(float (*As)[36], float (*Ws)[132],
                                          const float* __restrict__ src,
                                          const float* __restrict__ W,
                                          int n0, int N, int t, float acc[4][8]) {
    int tx = t & 15, ty = t >> 4;
    int ar = t >> 2, akq = (t & 3) * 8;
    int wk = t >> 3, wc = (t & 7) * 16;
    for (int kb = 0; kb < 4; ++kb) {
        int k0 = kb * 32;
        {
            int row = n0 + ar;
            float4 v0 = make_float4(0.f, 0.f, 0.f, 0.f), v1 = v0;
            if (row < N) {
                const float* ap = src + (size_t)row * HDIM + k0 + akq;
                v0 = *reinterpret_cast<const float4*>(ap);
                v1 = *reinterpret_cast<const float4*>(ap + 4);
            }
            *reinterpret_cast<float4*>(&As[ar][akq]) = v0;
            *reinterpret_cast<float4*>(&As[ar][akq + 4]) = v1;
        }
        {
            const float* wp = W + (size_t)(k0 + wk) * HDIM + wc;
#pragma unroll
            for (int jj = 0; jj < 4; jj++)
                *reinterpret_cast<float4*>(&Ws[wk][wc + 4 * jj]) =
                    *reinterpret_cast<const float4*>(wp + 4 * jj);
        }
        __syncthreads();
#pragma unroll
        for (int k4 = 0; k4 < 8; ++k4) {
            float4 av[4];
#pragma unroll
            for (int i = 0; i < 4; i++)
                av[i] = *reinterpret_cast<const float4*>(&As[ty * 4 + i][k4 * 4]);
#pragma unroll
            for (int kk = 0; kk < 4; kk++) {
                float4 w0 = *reinterpret_cast<const float4*>(&Ws[k4 * 4 + kk][tx * 4]);
                float4 w1 = *reinterpret_cast<const float4*>(&Ws[k4 * 4 + kk][64 + tx * 4]);
                float w[8] = {w0.x, w0.y, w0.z, w0.w, w1.x, w1.y, w1.z, w1.w};
#pragma unroll
                for (int i = 0; i < 4; i++) {
                    float avk = (kk == 0) ? av[i].x : (kk == 1) ? av[i].y
                                : (kk == 2) ? av[i].z : av[i].w;
#pragma unroll
                    for (int j = 0; j < 8; j++) acc[i][j] = fmaf(avk, w[j], acc[i][j]);
                }
            }
        }
        __syncthreads();
    }
}

// ---------- lin_k: out = src @ WT (no bias/relu), for pre-transforming source tables ----------
__global__ __launch_bounds__(256) void lin_k(const float* __restrict__ src,
                                             const float* __restrict__ WT,
                                             float* __restrict__ out, int N) {
    __shared__ __align__(16) float As[64][36];
    __shared__ __align__(16) float Ws[32][132];
    int t = threadIdx.x;
    int tx = t & 15, ty = t >> 4;
    int n0 = blockIdx.x * 64;
    float acc[4][8];
#pragma unroll
    for (int i = 0; i < 4; i++)
#pragma unroll
        for (int j = 0; j < 8; j++) acc[i][j] = 0.f;
    gemm_core(As, Ws, src, WT, n0, N, t, acc);
#pragma unroll
    for (int i = 0; i < 4; i++) {
        int row = n0 + ty * 4 + i;
        if (row < N) {
            float* op = out + (size_t)row * HDIM;
            *reinterpret_cast<float4*>(op + tx * 4) = make_float4(acc[i][0], acc[i][1], acc[i][2], acc[i][3]);
            *reinterpret_cast<float4*>(op + 64 + tx * 4) = make_float4(acc[i][4], acc[i][5], acc[i][6], acc[i][7]);
        }
    }
}

// ---------- dual-GEMM SAGE post (for dst=con, small): out = relu(agg@WlT + x@WrT + bl) ----------
__global__ __launch_bounds__(256) void sage_gemm_k(const float* __restrict__ agg,
                                                   const float* __restrict__ xdst,
                                                   const float* __restrict__ WlT,
                                                   const float* __restrict__ bl,
                                                   const float* __restrict__ WrT,
                                                   float* __restrict__ out, int N) {
    __shared__ __align__(16) float As[64][36];
    __shared__ __align__(16) float Ws[32][132];
    int t = threadIdx.x;
    int tx = t & 15, ty = t >> 4;
    int n0 = blockIdx.x * 64;
    float acc[4][8];
#pragma unroll
    for (int i = 0; i < 4; i++)
#pragma unroll
        for (int j = 0; j < 8; j++) acc[i][j] = 0.f;
    gemm_core(As, Ws, agg, WlT, n0, N, t, acc);
    gemm_core(As, Ws, xdst, WrT, n0, N, t, acc);
    float4 b0 = *reinterpret_cast<const float4*>(bl + tx * 4);
    float4 b1 = *reinterpret_cast<const float4*>(bl + 64 + tx * 4);
    float bb[8] = {b0.x, b0.y, b0.z, b0.w, b1.x, b1.y, b1.z, b1.w};
#pragma unroll
    for (int i = 0; i < 4; i++) {
        int row = n0 + ty * 4 + i;
        if (row < N) {
            float4 r0, r1;
            r0.x = fmaxf(acc[i][0] + bb[0], 0.f);
            r0.y = fmaxf(acc[i][1] + bb[1], 0.f);
            r0.z = fmaxf(acc[i][2] + bb[2], 0.f);
            r0.w = fmaxf(acc[i][3] + bb[3], 0.f);
            r1.x = fmaxf(acc[i][4] + bb[4], 0.f);
            r1.y = fmaxf(acc[i][5] + bb[5], 0.f);
            r1.z = fmaxf(acc[i][6] + bb[6], 0.f);
            r1.w = fmaxf(acc[i][7] + bb[7], 0.f);
            float* op = out + (size_t)row * HDIM;
            *reinterpret_cast<float4*>(op + tx * 4) = r0;
            *reinterpret_cast<float4*>(op + 64 + tx * 4) = r1;
        }
    }
}

// ---------- single-GEMM SAGE post with gathered-term add: out = relu(c0 + x@WrT + bl) ----------
__global__ __launch_bounds__(256) void sage_add_k(const float* __restrict__ c0,
                                                  const float* __restrict__ xdst,
                                                  const float* __restrict__ WrT,
                                                  const float* __restrict__ bl,
                                                  float* __restrict__ out, int N) {
    __shared__ __align__(16) float As[64][36];
    __shared__ __align__(16) float Ws[32][132];
    int t = threadIdx.x;
    int tx = t & 15, ty = t >> 4;
    int n0 = blockIdx.x * 64;
    float acc[4][8];
#pragma unroll
    for (int i = 0; i < 4; i++)
#pragma unroll
        for (int j = 0; j < 8; j++) acc[i][j] = 0.f;
    gemm_core(As, Ws, xdst, WrT, n0, N, t, acc);
    float4 b0 = *reinterpret_cast<const float4*>(bl + tx * 4);
    float4 b1 = *reinterpret_cast<const float4*>(bl + 64 + tx * 4);
    float bb[8] = {b0.x, b0.y, b0.z, b0.w, b1.x, b1.y, b1.z, b1.w};
#pragma unroll
    for (int i = 0; i < 4; i++) {
        int row = n0 + ty * 4 + i;
        if (row < N) {
            const float* cp = c0 + (size_t)row * HDIM;
            float4 c0a = *reinterpret_cast<const float4*>(cp + tx * 4);
            float4 c0b = *reinterpret_cast<const float4*>(cp + 64 + tx * 4);
            float4 r0, r1;
            r0.x = fmaxf(acc[i][0] + c0a.x + bb[0], 0.f);
            r0.y = fmaxf(acc[i][1] + c0a.y + bb[1], 0.f);
            r0.z = fmaxf(acc[i][2] + c0a.z + bb[2], 0.f);
            r0.w = fmaxf(acc[i][3] + c0a.w + bb[3], 0.f);
            r1.x = fmaxf(acc[i][4] + c0b.x + bb[4], 0.f);
            r1.y = fmaxf(acc[i][5] + c0b.y + bb[5], 0.f);
            r1.z = fmaxf(acc[i][6] + c0b.z + bb[6], 0.f);
            r1.w = fmaxf(acc[i][7] + c0b.w + bb[7], 0.f);
            float* op = out + (size_t)row * HDIM;
            *reinterpret_cast<float4*>(op + tx * 4) = r0;
            *reinterpret_cast<float4*>(op + 64 + tx * 4) = r1;
        }
    }
}

// ---------- conv2 single-GEMM + add + fused Q-head ----------
__global__ __launch_bounds__(256) void sage_add_q_k(const float* __restrict__ c0,
                                                    const float* __restrict__ xdst,
                                                    const float* __restrict__ WrT,
                                                    const float* __restrict__ bl,
                                                    const float* __restrict__ W1T,
                                                    const float* __restrict__ b1v,
                                                    const float* __restrict__ W2,
                                                    const float* __restrict__ b2,
                                                    float* __restrict__ out, int N) {
    __shared__ __align__(16) char smem[33792];  // union: (As 9216 + Ws 16896=26112) | H2 33792
    float (*As)[36] = reinterpret_cast<float(*)[36]>(smem);
    float (*Ws)[132] = reinterpret_cast<float(*)[132]>(smem + 9216);
    float (*H2)[132] = reinterpret_cast<float(*)[132]>(smem);
    int t = threadIdx.x;
    int tx = t & 15, ty = t >> 4;
    int n0 = blockIdx.x * 64;
    float acc[4][8];
#pragma unroll
    for (int i = 0; i < 4; i++)
#pragma unroll
        for (int j = 0; j < 8; j++) acc[i][j] = 0.f;
    gemm_core(As, Ws, xdst, WrT, n0, N, t, acc);
    // (core ends with syncthreads -> safe to overlay H2)
    {
        float4 b0 = *reinterpret_cast<const float4*>(bl + tx * 4);
        float4 b1 = *reinterpret_cast<const float4*>(bl + 64 + tx * 4);
        float bb[8] = {b0.x, b0.y, b0.z, b0.w, b1.x, b1.y, b1.z, b1.w};
#pragma unroll
        for (int i = 0; i < 4; i++) {
            int row = n0 + ty * 4 + i;
            float4 c0a = make_float4(0.f, 0.f, 0.f, 0.f), c0b = c0a;
            if (row < N) {
                const float* cp = c0 + (size_t)row * HDIM;
                c0a = *reinterpret_cast<const float4*>(cp + tx * 4);
                c0b = *reinterpret_cast<const float4*>(cp + 64 + tx * 4);
            }
            float4 r0, r1;
            r0.x = fmaxf(acc[i][0] + c0a.x + bb[0], 0.f);
            r0.y = fmaxf(acc[i][1] + c0a.y + bb[1], 0.f);
            r0.z = fmaxf(acc[i][2] + c0a.z + bb[2], 0.f);
            r0.w = fmaxf(acc[i][3] + c0a.w + bb[3], 0.f);
            r1.x = fmaxf(acc[i][4] + c0b.x + bb[4], 0.f);
            r1.y = fmaxf(acc[i][5] + c0b.y + bb[5], 0.f);
            r1.z = fmaxf(acc[i][6] + c0b.z + bb[6], 0.f);
            r1.w = fmaxf(acc[i][7] + c0b.w + bb[7], 0.f);
            float* hp = &H2[ty * 4 + i][0];
            *reinterpret_cast<float4*>(hp + tx * 4) = r0;
            *reinterpret_cast<float4*>(hp + 64 + tx * 4) = r1;
        }
    }
    __syncthreads();
    // phase 2: y = relu(H2 @ W1T + b1) [64x64]; q = y@W2 + b2
    int tx2 = t & 7, ty2 = t >> 3;
    float acc2[2][8];
#pragma unroll
    for (int i = 0; i < 2; i++)
#pragma unroll
        for (int j = 0; j < 8; j++) acc2[i][j] = 0.f;
    for (int k4 = 0; k4 < HDIM / 4; ++k4) {
        float4 a0 = *reinterpret_cast<const float4*>(&H2[ty2 * 2 + 0][k4 * 4]);
        float4 a1 = *reinterpret_cast<const float4*>(&H2[ty2 * 2 + 1][k4 * 4]);
        float a[2][4] = {{a0.x, a0.y, a0.z, a0.w}, {a1.x, a1.y, a1.z, a1.w}};
#pragma unroll
        for (int kk = 0; kk < 4; kk++) {
            const float* wp = W1T + (size_t)(k4 * 4 + kk) * 64 + tx2 * 8;
            float4 w0 = *reinterpret_cast<const float4*>(wp);
            float4 w1 = *reinterpret_cast<const float4*>(wp + 4);
            float w[8] = {w0.x, w0.y, w0.z, w0.w, w1.x, w1.y, w1.z, w1.w};
#pragma unroll
            for (int i = 0; i < 2; i++)
#pragma unroll
                for (int j = 0; j < 8; j++) acc2[i][j] = fmaf(a[i][kk], w[j], acc2[i][j]);
        }
    }
    {
        float4 c0v = *reinterpret_cast<const float4*>(b1v + tx2 * 8);
        float4 c1v = *reinterpret_cast<const float4*>(b1v + tx2 * 8 + 4);
        float bb1[8] = {c0v.x, c0v.y, c0v.z, c0v.w, c1v.x, c1v.y, c1v.z, c1v.w};
        float4 d0 = *reinterpret_cast<const float4*>(W2 + tx2 * 8);
        float4 d1 = *reinterpret_cast<const float4*>(W2 + tx2 * 8 + 4);
        float w2[8] = {d0.x, d0.y, d0.z, d0.w, d1.x, d1.y, d1.z, d1.w};
#pragma unroll
        for (int i = 0; i < 2; i++) {
            float v = 0.f;
#pragma unroll
            for (int j = 0; j < 8; j++) v = fmaf(fmaxf(acc2[i][j] + bb1[j], 0.f), w2[j], v);
            v += __shfl_xor(v, 1);
            v += __shfl_xor(v, 2);
            v += __shfl_xor(v, 4);
            int row = n0 + ty2 * 2 + i;
            if (tx2 == 0 && row < N) out[row] = v + b2[0];
        }
    }
}

extern "C" void kernel_launch(void* const* d_in, const int* in_sizes, int n_in,
                              void* d_out, int out_size, void* d_ws, size_t ws_size,
                              hipStream_t stream) {
    const float* x_col = (const float*)d_in[0];
    const float* x_con = (const float*)d_in[1];
    const int* edge_col = (const int*)d_in[2];
    const int* edge_con = (const int*)d_in[3];
    const float* W_col = (const float*)d_in[4];
    const float* b_col = (const float*)d_in[5];
    const float* W_con = (const float*)d_in[6];
    const float* b_con = (const float*)d_in[7];
    const float* c1_cn_Wl = (const float*)d_in[8];
    const float* c1_cn_bl = (const float*)d_in[9];
    const float* c1_cn_Wr = (const float*)d_in[10];
    const float* c1_nc_Wl = (const float*)d_in[11];
    const float* c1_nc_bl = (const float*)d_in[12];
    const float* c1_nc_Wr = (const float*)d_in[13];
    // d_in[14..16] = c2_cn_* : dead (h_con2 deleted in reference)
    const float* c2_nc_Wl = (const float*)d_in[17];
    const float* c2_nc_bl = (const float*)d_in[18];
    const float* c2_nc_Wr = (const float*)d_in[19];
    const float* q_W1 = (const float*)d_in[20];
    const float* q_b1 = (const float*)d_in[21];
    const float* q_W2 = (const float*)d_in[22];
    const float* q_b2 = (const float*)d_in[23];
    float* out = (float*)d_out;
    const int E = in_sizes[2];

    float* ws = (float*)d_ws;
    size_t o = 0;
    float* h_col = ws + o;   o += (size_t)N_COL * HDIM;
    float* h_con = ws + o;   o += (size_t)N_CON * HDIM;
    float* n_con = ws + o;   o += (size_t)N_CON * HDIM;
    float* n_col = ws + o;   o += (size_t)N_COL * HDIM;
    float* bufA = ws + o;    o += (size_t)N_COL * HDIM;  // agg_con / aggW_col (reused)
    float* bufB = ws + o;    o += (size_t)N_CON * HDIM;  // transformed source tables (reused)
    float* W_colT = ws + o;  o += 16 * HDIM;
    float* W_conT = ws + o;  o += 8 * HDIM;
    float* c1_cn_WlT = ws + o; o += HDIM * HDIM;
    float* c1_cn_WrT = ws + o; o += HDIM * HDIM;
    float* c1_nc_WlT = ws + o; o += HDIM * HDIM;
    float* c1_nc_WrT = ws + o; o += HDIM * HDIM;
    float* c2_nc_WlT = ws + o; o += HDIM * HDIM;
    float* c2_nc_WrT = ws + o; o += HDIM * HDIM;
    float* q_W1T = ws + o;     o += HDIM * 64;
    // CSR scratch (int views)
    int* iws = (int*)(ws + o);
    size_t io = 0;
    int* cnt_col = iws + io;  io += N_COL;
    int* cnt_con = iws + io;  io += N_CON;
    int* offs_col = iws + io; io += N_COL;
    int* offs_con = iws + io; io += N_CON;
    int* cursor = iws + io;   io += N_COL;
    int* partials = iws + io; io += 256;
    int* srclist_col = iws + io; io += E;   // dst=col buckets, stores con src idx
    int* srclist_con = iws + io; io += E;   // dst=con buckets, stores col src idx

    auto T = [&](const float* s, float* d, int R, int C) {
        transpose_k<<<(R * C + 255) / 256, 256, 0, stream>>>(s, d, R, C);
    };
    T(W_col, W_colT, HDIM, 16);
    T(W_con, W_conT, HDIM, 8);
    T(c1_cn_Wl, c1_cn_WlT, HDIM, HDIM);
    T(c1_cn_Wr, c1_cn_WrT, HDIM, HDIM);
    T(c1_nc_Wl, c1_nc_WlT, HDIM, HDIM);
    T(c1_nc_Wr, c1_nc_WrT, HDIM, HDIM);
    T(c2_nc_Wl, c2_nc_WlT, HDIM, HDIM);
    T(c2_nc_Wr, c2_nc_WrT, HDIM, HDIM);
    T(q_W1, q_W1T, 64, HDIM);

    encoder_k<16><<<((size_t)N_COL * HDIM + 255) / 256, 256, 0, stream>>>(x_col, W_colT, b_col, h_col, N_COL);
    encoder_k<8><<<((size_t)N_CON * HDIM + 255) / 256, 256, 0, stream>>>(x_con, W_conT, b_con, h_con, N_CON);

    // ---- CSR build (both directions) ----
    hipMemsetAsync(cnt_col, 0, (N_COL + N_CON) * sizeof(int), stream);
    count_k<<<(E + 255) / 256, 256, 0, stream>>>(edge_col, edge_con, cnt_col, cnt_con, E);

    int nb_col = (N_COL + SCAN_B - 1) / SCAN_B;  // 98
    int nb_con = (N_CON + SCAN_B - 1) / SCAN_B;  // 20
    scan1_k<<<nb_col, 256, 0, stream>>>(cnt_col, N_COL, offs_col, partials);
    scan2_k<<<1, 256, 0, stream>>>(partials, nb_col);
    scan3_k<<<(N_COL + 255) / 256, 256, 0, stream>>>(offs_col, N_COL, partials);
    scan1_k<<<nb_con, 256, 0, stream>>>(cnt_con, N_CON, offs_con, partials);
    scan2_k<<<1, 256, 0, stream>>>(partials, nb_con);
    scan3_k<<<(N_CON + 255) / 256, 256, 0, stream>>>(offs_con, N_CON, partials);

    hipMemsetAsync(cursor, 0, N_COL * sizeof(int), stream);
    fill_k<<<(E + 255) / 256, 256, 0, stream>>>(edge_con, edge_col, offs_col, cursor, srclist_col, E);
    hipMemsetAsync(cursor, 0, N_CON * sizeof(int), stream);
    fill_k<<<(E + 255) / 256, 256, 0, stream>>>(edge_col, edge_con, offs_con, cursor, srclist_con, E);

    // ---- conv1 col->con (dst small: classic gather + dual GEMM) ----
    gather_mean_k<<<(N_CON + 3) / 4, 256, 0, stream>>>(h_col, srclist_con, offs_con, cnt_con, bufA, N_CON);
    sage_gemm_k<<<(N_CON + 63) / 64, 256, 0, stream>>>(bufA, h_con, c1_cn_WlT, c1_cn_bl, c1_cn_WrT, n_con, N_CON);

    // ---- conv1 con->col (dst large: transform-then-gather, single GEMM + add) ----
    lin_k<<<(N_CON + 63) / 64, 256, 0, stream>>>(h_con, c1_nc_WlT, bufB, N_CON);
    gather_mean_k<<<(N_COL + 3) / 4, 256, 0, stream>>>(bufB, srclist_col, offs_col, cnt_col, bufA, N_COL);
    sage_add_k<<<(N_COL + 63) / 64, 256, 0, stream>>>(bufA, h_col, c1_nc_WrT, c1_nc_bl, n_col, N_COL);

    // ---- conv2 con->col + fused Q-head ----
    lin_k<<<(N_CON + 63) / 64, 256, 0, stream>>>(n_con, c2_nc_WlT, bufB, N_CON);
    gather_mean_k<<<(N_COL + 3) / 4, 256, 0, stream>>>(bufB, srclist_col, offs_col, cnt_col, bufA, N_COL);
    sage_add_q_k<<<(N_COL + 63) / 64, 256, 0, stream>>>(bufA, n_col, c2_nc_WrT, c2_nc_bl,
                                                        q_W1T, q_b1, q_W2, q_b2, out, N_COL);
}